// Round 12
// baseline (161.039 us; speedup 1.0000x reference)
//
#include <hip/hip_runtime.h>

// GRU fused, MI355X/gfx950 — round 12.
// r11 post-mortem: (256,2) caps at 128 arch VGPRs (r2/r6/r11 all show
// VGPR_Count=128) -> 4-wave/120-wreg config spills 16MB. Empirical caps:
// (512,4)->64, (256,2)->128, (512,2)->no spill at <=108 used (r7/r10).
// r12 = the untested matrix cell: LEAN math x 2 desynced blocks/CU,
// spill-free. r10 structure exactly (8 waves x 16 cols, 60 wregs,
// mt-serial tiles) with MB=32/mt=2, grid 512 -> 2 blocks/CU, LB(512,2).
// Same per-CU rows/step as r10 (64) but two independent barrier groups:
// block A's barrier drain / gate-VALU overlaps block B's MFMA issue.

#define B_  16384
#define T_  28
#define F_  28
#define H_  128
#define C_  10
#define MB  32     // batch rows per block (2 tiles of 16)
#define MT  2      // batch tiles per wave
#define LHS 136    // lh row stride in ushorts (272 B; balanced banks for b128/b64)

typedef short  short8  __attribute__((ext_vector_type(8)));
typedef float  f32x4   __attribute__((ext_vector_type(4)));
typedef unsigned uint4v __attribute__((ext_vector_type(4)));

__device__ __forceinline__ unsigned short f2bf(float f) {   // RNE fp32->bf16
    unsigned u = __builtin_bit_cast(unsigned, f);
    u += 0x7fffu + ((u >> 16) & 1u);
    return (unsigned short)(u >> 16);
}
__device__ __forceinline__ float bf2f(unsigned short h) {
    unsigned u = ((unsigned)h) << 16;
    return __builtin_bit_cast(float, u);
}
__device__ __forceinline__ unsigned cvt_pk_bf16(float lo, float hi) {
    unsigned r;
    asm("v_cvt_pk_bf16_f32 %0, %1, %2" : "=v"(r) : "v"(lo), "v"(hi));
    return r;
}

#define MS (-1.442695040888963f)   // z,r pre-scale (sig(x)=rcp(1+exp2(-x/ln2)))
#define TS ( 2.885390081777927f)   // tanh pre-scale (tanh=1-2*rcp(1+exp2(2x/ln2)))

__global__ __launch_bounds__(512, 2)
void gru_fused(const float* __restrict__ x,     // (B,T,F)
               const float* __restrict__ wk,    // (F,3H) = (28,384)
               const float* __restrict__ wrk,   // (H,3H) = (128,384)
               const float* __restrict__ bias,  // (2,3H)
               const float* __restrict__ dw,    // (H,C)
               const float* __restrict__ db,    // (C,)
               float* __restrict__ out)         // (B,C)
{
    // ---- LDS (~24 KB) -> 2 blocks/CU ----
    __shared__ __align__(16) unsigned short lh[2][MB*LHS];      // 17408 B, double-buffered
    __shared__ float ldw[H_*C_];                                // 5120 B
    __shared__ float llog[MB][C_];                              // 1280 B

    const int tid  = threadIdx.x;
    const int base = blockIdx.x * MB;
    const int lane = tid & 63;
    const int wc   = tid >> 6;    // wave id 0..7 -> 16-column slice
    const int n    = lane & 15;   // B-operand outer (batch within tile) / D col
    const int q    = lane >> 4;   // MFMA quad
    const int col  = wc*16 + n;   // weight column (A operand)

    // ---- loop-invariant weight fragments -> REGISTERS (60 VGPR/wave) ----
    // A-frag: elem(lane,j) = W'[k = kb*32 + q*8 + j][col]
    // W' = W * MS (z,r) or W * TS (h). x-kernel k==28 row carries the bias.
    short8 wzr[4], wrr[4], whr[4];   // W_rec per kb: 48 VGPR
    short8 xzr, xrr, xhr;            // kernel (K pad 28->32, k28=bias): 12 VGPR
    {
        #pragma unroll
        for (int kb = 0; kb < 4; ++kb) {
            const int k0 = kb*32 + q*8;
            short8 vz, vr, vh;
            #pragma unroll
            for (int j = 0; j < 8; ++j) {
                const float* wp = wrk + (size_t)(k0 + j)*384 + col;
                vz[j] = (short)f2bf(wp[0]   * MS);
                vr[j] = (short)f2bf(wp[128] * MS);
                vh[j] = (short)f2bf(wp[256] * TS);
            }
            wzr[kb] = vz; wrr[kb] = vr; whr[kb] = vh;
        }
        short8 vz, vr, vh;
        #pragma unroll
        for (int j = 0; j < 8; ++j) {
            const int k = q*8 + j;
            if (k < F_) {
                const float* wp = wk + (size_t)k*384 + col;
                vz[j] = (short)f2bf(wp[0]   * MS);
                vr[j] = (short)f2bf(wp[128] * MS);
                vh[j] = (short)f2bf(wp[256] * TS);
            } else if (k == F_) {   // bias row (B-frag has 1.0 here)
                vz[j] = (short)f2bf((bias[col]       + bias[384 + col]) * MS);
                vr[j] = (short)f2bf((bias[128 + col] + bias[512 + col]) * MS);
                vh[j] = (short)f2bf( bias[256 + col]                    * TS);
            } else { vz[j] = 0; vr[j] = 0; vh[j] = 0; }
        }
        xzr = vz; xrr = vr; xhr = vh;
    }

    // br_h (rec-h acc init), pre-scaled: 4 VGPR
    f32x4 bh4;
    #pragma unroll
    for (int reg = 0; reg < 4; ++reg)
        bh4[reg] = bias[640 + wc*16 + q*4 + reg] * TS;

    // ---- dense weights / h0 ----
    for (int i = tid; i < H_*C_; i += 512) ldw[i] = dw[i];
    for (int i = tid; i < MB*LHS/2; i += 512) ((unsigned*)lh[0])[i] = 0u;

    __syncthreads();   // init visible

    float hm[MT][4];              // fp32 h master: unit wc*16+q*4+reg, batch mt*16+n
    #pragma unroll
    for (int mt = 0; mt < MT; ++mt)
        #pragma unroll
        for (int r = 0; r < 4; ++r) hm[mt][r] = 0.f;

    // per-mt x row pointers + x prefetch for t=0 (16 VGPR)
    const int xo1 = q*8;
    const int xo2 = (q < 3) ? q*8 + 4 : 24;   // clamped: in-bounds garbage x zero-weight
    const bool q3 = (q == 3);
    const float* xrw[MT];
    float4 xa0[MT], xa1[MT];
    #pragma unroll
    for (int mt = 0; mt < MT; ++mt) {
        xrw[mt] = x + (size_t)(base + mt*16 + n)*(T_*F_);
        xa0[mt] = *(const float4*)(xrw[mt] + xo1);
        xa1[mt] = *(const float4*)(xrw[mt] + xo2);
    }

    const int wbase = wc*16 + q*4;    // unit base this lane owns

    #pragma unroll 1
    for (int t = 0; t < T_; ++t) {
        const unsigned short* __restrict__ lhr = lh[t & 1];
        unsigned short* __restrict__ lhw = lh[(t + 1) & 1];
        const bool pn = (t + 1 < T_);

        #pragma unroll
        for (int mt = 0; mt < MT; ++mt) {
            // x B-frag from prefetched regs (4x cvt_pk; k==28 slot = 1.0 bias mult)
            uint4v xv;
            xv[0] = cvt_pk_bf16(xa0[mt].x, xa0[mt].y);
            xv[1] = cvt_pk_bf16(xa0[mt].z, xa0[mt].w);
            xv[2] = q3 ? 0x3f80u : cvt_pk_bf16(xa1[mt].x, xa1[mt].y);
            xv[3] = cvt_pk_bf16(xa1[mt].z, xa1[mt].w);
            const short8 xbv = __builtin_bit_cast(short8, xv);

            // issue next step's x loads for this mt (full step of latency cover)
            if (pn) {
                xa0[mt] = *(const float4*)(xrw[mt] + (t+1)*F_ + xo1);
                xa1[mt] = *(const float4*)(xrw[mt] + (t+1)*F_ + xo2);
            }

            // h B-frags for this tile: 4x b128, conflict-free
            const int rbase = (mt*16 + n)*LHS;
            short8 hb[4];
            #pragma unroll
            for (int kb = 0; kb < 4; ++kb)
                hb[kb] = *(const short8*)&lhr[rbase + kb*32 + q*8];

            f32x4 az = (f32x4){0.f,0.f,0.f,0.f};
            f32x4 ag = (f32x4){0.f,0.f,0.f,0.f};
            f32x4 ax = (f32x4){0.f,0.f,0.f,0.f};
            f32x4 ah = bh4;
            #pragma unroll
            for (int kb = 0; kb < 4; ++kb) {
                az = __builtin_amdgcn_mfma_f32_16x16x32_bf16(wzr[kb], hb[kb], az, 0,0,0);
                ag = __builtin_amdgcn_mfma_f32_16x16x32_bf16(wrr[kb], hb[kb], ag, 0,0,0);
                ah = __builtin_amdgcn_mfma_f32_16x16x32_bf16(whr[kb], hb[kb], ah, 0,0,0);
            }
            az = __builtin_amdgcn_mfma_f32_16x16x32_bf16(xzr, xbv, az, 0,0,0);
            ag = __builtin_amdgcn_mfma_f32_16x16x32_bf16(xrr, xbv, ag, 0,0,0);
            ax = __builtin_amdgcn_mfma_f32_16x16x32_bf16(xhr, xbv, ax, 0,0,0);

            // gates (pre-scaled accs): z=rcp(1+exp2(az)), hh=1-2*rcp(1+exp2(ax+r*ah))
            float hn[4];
            #pragma unroll
            for (int reg = 0; reg < 4; ++reg) {
                float z  = __builtin_amdgcn_rcpf(1.0f + __builtin_amdgcn_exp2f(az[reg]));
                float r  = __builtin_amdgcn_rcpf(1.0f + __builtin_amdgcn_exp2f(ag[reg]));
                float ta = ax[reg] + r * ah[reg];
                float hh = 1.0f - 2.0f * __builtin_amdgcn_rcpf(1.0f + __builtin_amdgcn_exp2f(ta));
                float hv = hh + z * (hm[mt][reg] - hh);
                hm[mt][reg] = hv; hn[reg] = hv;
            }
            uint2 pk;
            pk.x = cvt_pk_bf16(hn[0], hn[1]);
            pk.y = cvt_pk_bf16(hn[2], hn[3]);
            *(uint2*)&lhw[rbase + wbase] = pk;
        }

        __syncthreads();   // h_{t+1} published
    }

    // ---- dense + softmax epilogue (final h in lh[0]: last write t=27 -> (27+1)&1) ----
    for (int i = tid; i < MB*C_; i += 512) {
        const int row = i / C_, c = i - row*C_;
        float s = db[c];
        #pragma unroll
        for (int u0 = 0; u0 < H_; u0 += 8) {
            short8 hv = *(const short8*)&lh[0][row*LHS + u0];
            #pragma unroll
            for (int j = 0; j < 8; ++j)
                s += bf2f((unsigned short)hv[j]) * ldw[(u0+j)*C_ + c];
        }
        llog[row][c] = s;
    }
    __syncthreads();
    if (tid < MB) {
        const int row = tid;
        float m = llog[row][0];
        #pragma unroll
        for (int c = 1; c < C_; ++c) m = fmaxf(m, llog[row][c]);
        float e[C_], s = 0.f;
        #pragma unroll
        for (int c = 0; c < C_; ++c) {
            e[c] = __builtin_amdgcn_exp2f((llog[row][c] - m) * 1.442695040888963f);
            s += e[c];
        }
        const float inv = __builtin_amdgcn_rcpf(s);
        float* o = out + (size_t)(base + row)*C_;
        #pragma unroll
        for (int c = 0; c < C_; ++c) o[c] = e[c] * inv;
    }
}

extern "C" void kernel_launch(void* const* d_in, const int* in_sizes, int n_in,
                              void* d_out, int out_size, void* d_ws, size_t ws_size,
                              hipStream_t stream) {
    const float* x   = (const float*)d_in[0];
    const float* wk  = (const float*)d_in[1];
    const float* wrk = (const float*)d_in[2];
    const float* bs  = (const float*)d_in[3];
    const float* dw  = (const float*)d_in[4];
    const float* db  = (const float*)d_in[5];
    (void)in_sizes; (void)n_in; (void)out_size; (void)d_ws; (void)ws_size;
    gru_fused<<<dim3(B_/MB), dim3(512), 0, stream>>>(x, wk, wrk, bs, dw, db, (float*)d_out);
}

// Round 13
// 149.280 us; speedup vs baseline: 1.0788x; 1.0788x over previous
//
#include <hip/hip_runtime.h>

// GRU fused, MI355X/gfx950 — round 13.
// r12 post-mortem: 2 desynced blocks/CU spill-free = 95us > r10's 88us.
// Occupancy family dead (3 strikes). r10 arithmetic: MFMA pipe 0.97us +
// VALU 1.4us per 3.15us step = pipes running SEQUENTIALLY (lockstep
// phases). r13 = r10 + intra-wave software pipeline: gates(mt) overlap
// MFMA(mt+1) in the same instruction stream, so VALU and matrix pipes
// are fed simultaneously regardless of wave phase alignment.
//   MFMA(0); MFMA(1)|GATES(0); ... MFMA(3)|GATES(2); GATES(3); barrier.
// Also: acc-init movs removed (chains seeded via C=0 / C=bh4 on the
// first MFMA), x-MFMA first in each chain.

#define B_  16384
#define T_  28
#define F_  28
#define H_  128
#define C_  10
#define MB  64     // batch rows per block (4 tiles of 16)
#define MT  4      // batch tiles per wave
#define LHS 136    // lh row stride in ushorts (272 B; balanced banks for b128/b64)

typedef short  short8  __attribute__((ext_vector_type(8)));
typedef float  f32x4   __attribute__((ext_vector_type(4)));
typedef unsigned uint4v __attribute__((ext_vector_type(4)));

__device__ __forceinline__ unsigned short f2bf(float f) {   // RNE fp32->bf16
    unsigned u = __builtin_bit_cast(unsigned, f);
    u += 0x7fffu + ((u >> 16) & 1u);
    return (unsigned short)(u >> 16);
}
__device__ __forceinline__ float bf2f(unsigned short h) {
    unsigned u = ((unsigned)h) << 16;
    return __builtin_bit_cast(float, u);
}
__device__ __forceinline__ unsigned cvt_pk_bf16(float lo, float hi) {
    unsigned r;
    asm("v_cvt_pk_bf16_f32 %0, %1, %2" : "=v"(r) : "v"(lo), "v"(hi));
    return r;
}

#define MS (-1.442695040888963f)   // z,r pre-scale (sig(x)=rcp(1+exp2(-x/ln2)))
#define TS ( 2.885390081777927f)   // tanh pre-scale (tanh=1-2*rcp(1+exp2(2x/ln2)))

__global__ __launch_bounds__(512, 2)
void gru_fused(const float* __restrict__ x,     // (B,T,F)
               const float* __restrict__ wk,    // (F,3H) = (28,384)
               const float* __restrict__ wrk,   // (H,3H) = (128,384)
               const float* __restrict__ bias,  // (2,3H)
               const float* __restrict__ dw,    // (H,C)
               const float* __restrict__ db,    // (C,)
               float* __restrict__ out)         // (B,C)
{
    // ---- LDS (~43 KB) ----
    __shared__ __align__(16) unsigned short lh[2][MB*LHS];      // 34816 B, double-buffered
    __shared__ float ldw[H_*C_];                                // 5120 B
    __shared__ float llog[MB][C_];                              // 2560 B

    const int tid  = threadIdx.x;
    const int base = blockIdx.x * MB;
    const int lane = tid & 63;
    const int wc   = tid >> 6;    // wave id 0..7 -> 16-column slice
    const int n    = lane & 15;   // B-operand outer (batch within tile) / D col
    const int q    = lane >> 4;   // MFMA quad
    const int col  = wc*16 + n;   // weight column (A operand)

    // ---- loop-invariant weight fragments -> REGISTERS (60 VGPR/wave) ----
    short8 wzr[4], wrr[4], whr[4];   // W_rec per kb: 48 VGPR (pre-scaled MS/TS)
    short8 xzr, xrr, xhr;            // kernel (K pad 28->32, k28=bias): 12 VGPR
    {
        #pragma unroll
        for (int kb = 0; kb < 4; ++kb) {
            const int k0 = kb*32 + q*8;
            short8 vz, vr, vh;
            #pragma unroll
            for (int j = 0; j < 8; ++j) {
                const float* wp = wrk + (size_t)(k0 + j)*384 + col;
                vz[j] = (short)f2bf(wp[0]   * MS);
                vr[j] = (short)f2bf(wp[128] * MS);
                vh[j] = (short)f2bf(wp[256] * TS);
            }
            wzr[kb] = vz; wrr[kb] = vr; whr[kb] = vh;
        }
        short8 vz, vr, vh;
        #pragma unroll
        for (int j = 0; j < 8; ++j) {
            const int k = q*8 + j;
            if (k < F_) {
                const float* wp = wk + (size_t)k*384 + col;
                vz[j] = (short)f2bf(wp[0]   * MS);
                vr[j] = (short)f2bf(wp[128] * MS);
                vh[j] = (short)f2bf(wp[256] * TS);
            } else if (k == F_) {   // bias row (B-frag has 1.0 here)
                vz[j] = (short)f2bf((bias[col]       + bias[384 + col]) * MS);
                vr[j] = (short)f2bf((bias[128 + col] + bias[512 + col]) * MS);
                vh[j] = (short)f2bf( bias[256 + col]                    * TS);
            } else { vz[j] = 0; vr[j] = 0; vh[j] = 0; }
        }
        xzr = vz; xrr = vr; xhr = vh;
    }

    // br_h (rec-h chain C-seed), pre-scaled: 4 VGPR
    f32x4 bh4;
    #pragma unroll
    for (int reg = 0; reg < 4; ++reg)
        bh4[reg] = bias[640 + wc*16 + q*4 + reg] * TS;
    const f32x4 ZERO4 = (f32x4){0.f, 0.f, 0.f, 0.f};

    // ---- dense weights / h0 ----
    for (int i = tid; i < H_*C_; i += 512) ldw[i] = dw[i];
    for (int i = tid; i < MB*LHS/2; i += 512) ((unsigned*)lh[0])[i] = 0u;

    __syncthreads();   // init visible

    float hm[MT][4];              // fp32 h master: unit wc*16+q*4+reg, batch mt*16+n
    #pragma unroll
    for (int mt = 0; mt < MT; ++mt)
        #pragma unroll
        for (int r = 0; r < 4; ++r) hm[mt][r] = 0.f;

    // per-mt x row pointers + x prefetch for t=0 (32 VGPR)
    const int xo1 = q*8;
    const int xo2 = (q < 3) ? q*8 + 4 : 24;   // clamped: in-bounds garbage x zero-weight
    const bool q3 = (q == 3);
    const float* xrw[MT];
    float4 xa0[MT], xa1[MT];
    #pragma unroll
    for (int mt = 0; mt < MT; ++mt) {
        xrw[mt] = x + (size_t)(base + mt*16 + n)*(T_*F_);
        xa0[mt] = *(const float4*)(xrw[mt] + xo1);
        xa1[mt] = *(const float4*)(xrw[mt] + xo2);
    }

    const int wbase = wc*16 + q*4;    // unit base this lane owns

    f32x4 az[MT], ag[MT], ax[MT], ah[MT];   // all-mt accumulators (64 VGPR)

// issue one mt tile's x-frag build + prefetch + h-frag reads + 15 MFMAs
#define MFMA_CHUNK(mt)                                                          \
    {                                                                           \
        uint4v xv;                                                              \
        xv[0] = cvt_pk_bf16(xa0[mt].x, xa0[mt].y);                              \
        xv[1] = cvt_pk_bf16(xa0[mt].z, xa0[mt].w);                              \
        xv[2] = q3 ? 0x3f80u : cvt_pk_bf16(xa1[mt].x, xa1[mt].y);               \
        xv[3] = cvt_pk_bf16(xa1[mt].z, xa1[mt].w);                              \
        const short8 xbv = __builtin_bit_cast(short8, xv);                      \
        if (pn) {                                                               \
            xa0[mt] = *(const float4*)(xrw[mt] + (t+1)*F_ + xo1);               \
            xa1[mt] = *(const float4*)(xrw[mt] + (t+1)*F_ + xo2);               \
        }                                                                       \
        const int rbase = ((mt)*16 + n)*LHS;                                    \
        short8 hb0 = *(const short8*)&lhr[rbase +  0 + q*8];                    \
        short8 hb1 = *(const short8*)&lhr[rbase + 32 + q*8];                    \
        short8 hb2 = *(const short8*)&lhr[rbase + 64 + q*8];                    \
        short8 hb3 = *(const short8*)&lhr[rbase + 96 + q*8];                    \
        az[mt] = __builtin_amdgcn_mfma_f32_16x16x32_bf16(xzr, xbv, ZERO4, 0,0,0);\
        ag[mt] = __builtin_amdgcn_mfma_f32_16x16x32_bf16(xrr, xbv, ZERO4, 0,0,0);\
        ax[mt] = __builtin_amdgcn_mfma_f32_16x16x32_bf16(xhr, xbv, ZERO4, 0,0,0);\
        ah[mt] = __builtin_amdgcn_mfma_f32_16x16x32_bf16(whr[0], hb0, bh4, 0,0,0);\
        az[mt] = __builtin_amdgcn_mfma_f32_16x16x32_bf16(wzr[0], hb0, az[mt], 0,0,0);\
        ag[mt] = __builtin_amdgcn_mfma_f32_16x16x32_bf16(wrr[0], hb0, ag[mt], 0,0,0);\
        ah[mt] = __builtin_amdgcn_mfma_f32_16x16x32_bf16(whr[1], hb1, ah[mt], 0,0,0);\
        az[mt] = __builtin_amdgcn_mfma_f32_16x16x32_bf16(wzr[1], hb1, az[mt], 0,0,0);\
        ag[mt] = __builtin_amdgcn_mfma_f32_16x16x32_bf16(wrr[1], hb1, ag[mt], 0,0,0);\
        ah[mt] = __builtin_amdgcn_mfma_f32_16x16x32_bf16(whr[2], hb2, ah[mt], 0,0,0);\
        az[mt] = __builtin_amdgcn_mfma_f32_16x16x32_bf16(wzr[2], hb2, az[mt], 0,0,0);\
        ag[mt] = __builtin_amdgcn_mfma_f32_16x16x32_bf16(wrr[2], hb2, ag[mt], 0,0,0);\
        ah[mt] = __builtin_amdgcn_mfma_f32_16x16x32_bf16(whr[3], hb3, ah[mt], 0,0,0);\
        az[mt] = __builtin_amdgcn_mfma_f32_16x16x32_bf16(wzr[3], hb3, az[mt], 0,0,0);\
        ag[mt] = __builtin_amdgcn_mfma_f32_16x16x32_bf16(wrr[3], hb3, ag[mt], 0,0,0);\
    }

// gates + h update + packed LDS write for one mt tile
#define GATES_CHUNK(mt)                                                         \
    {                                                                           \
        float hn[4];                                                            \
        _Pragma("unroll")                                                       \
        for (int reg = 0; reg < 4; ++reg) {                                     \
            float z  = __builtin_amdgcn_rcpf(1.0f + __builtin_amdgcn_exp2f(az[mt][reg])); \
            float r  = __builtin_amdgcn_rcpf(1.0f + __builtin_amdgcn_exp2f(ag[mt][reg])); \
            float ta = ax[mt][reg] + r * ah[mt][reg];                           \
            float hh = 1.0f - 2.0f * __builtin_amdgcn_rcpf(1.0f + __builtin_amdgcn_exp2f(ta)); \
            float hv = hh + z * (hm[mt][reg] - hh);                             \
            hm[mt][reg] = hv; hn[reg] = hv;                                     \
        }                                                                       \
        uint2 pk;                                                               \
        pk.x = cvt_pk_bf16(hn[0], hn[1]);                                       \
        pk.y = cvt_pk_bf16(hn[2], hn[3]);                                       \
        *(uint2*)&lhw[((mt)*16 + n)*LHS + wbase] = pk;                          \
    }

    #pragma unroll 1
    for (int t = 0; t < T_; ++t) {
        const unsigned short* __restrict__ lhr = lh[t & 1];
        unsigned short* __restrict__ lhw = lh[(t + 1) & 1];
        const bool pn = (t + 1 < T_);

        // software pipeline: gates(mt) overlap MFMA(mt+1) on separate pipes
        MFMA_CHUNK(0)
        MFMA_CHUNK(1) GATES_CHUNK(0)
        MFMA_CHUNK(2) GATES_CHUNK(1)
        MFMA_CHUNK(3) GATES_CHUNK(2)
        GATES_CHUNK(3)

        __syncthreads();   // h_{t+1} published
    }

    // ---- dense + softmax epilogue (final h in lh[0]: last write t=27 -> (27+1)&1) ----
    for (int i = tid; i < MB*C_; i += 512) {
        const int row = i / C_, c = i - row*C_;
        float s = db[c];
        #pragma unroll
        for (int u0 = 0; u0 < H_; u0 += 8) {
            short8 hv = *(const short8*)&lh[0][row*LHS + u0];
            #pragma unroll
            for (int j = 0; j < 8; ++j)
                s += bf2f((unsigned short)hv[j]) * ldw[(u0+j)*C_ + c];
        }
        llog[row][c] = s;
    }
    __syncthreads();
    if (tid < MB) {
        const int row = tid;
        float m = llog[row][0];
        #pragma unroll
        for (int c = 1; c < C_; ++c) m = fmaxf(m, llog[row][c]);
        float e[C_], s = 0.f;
        #pragma unroll
        for (int c = 0; c < C_; ++c) {
            e[c] = __builtin_amdgcn_exp2f((llog[row][c] - m) * 1.442695040888963f);
            s += e[c];
        }
        const float inv = __builtin_amdgcn_rcpf(s);
        float* o = out + (size_t)(base + row)*C_;
        #pragma unroll
        for (int c = 0; c < C_; ++c) o[c] = e[c] * inv;
    }
}

extern "C" void kernel_launch(void* const* d_in, const int* in_sizes, int n_in,
                              void* d_out, int out_size, void* d_ws, size_t ws_size,
                              hipStream_t stream) {
    const float* x   = (const float*)d_in[0];
    const float* wk  = (const float*)d_in[1];
    const float* wrk = (const float*)d_in[2];
    const float* bs  = (const float*)d_in[3];
    const float* dw  = (const float*)d_in[4];
    const float* db  = (const float*)d_in[5];
    (void)in_sizes; (void)n_in; (void)out_size; (void)d_ws; (void)ws_size;
    gru_fused<<<dim3(B_/MB), dim3(512), 0, stream>>>(x, wk, wrk, bs, dw, db, (float*)d_out);
}